// Round 8
// baseline (454.033 us; speedup 1.0000x reference)
//
#include <hip/hip_runtime.h>

#define NROW 6
#define NCOL 6
#define BATCH 1024
#define NSITE 36

// Pre-transpose T[site][spin][u=x][r=gp][d=z][l=g] into
// Tm[(site*2+spin)*256 + (gp*4+z)*16 + (g*4+x)]  (73,728 B in d_ws) so the
// main kernel's M rows are contiguous float4s at wave-uniform addresses.
__global__ void peps_reorder_kernel(const float* __restrict__ T,
                                    float* __restrict__ Tm)
{
    int idx = blockIdx.x * 256 + threadIdx.x;   // [0, 18432)
    if (idx >= NSITE * 2 * 256) return;
    int i  = idx & 15;          // i = g*4 + x
    int o  = (idx >> 4) & 15;   // o = gp*4 + z
    int sp = (idx >> 8) & 1;
    int st = idx >> 9;
    int g = i >> 2, x = i & 3, gp = o >> 2, z = o & 3;
    Tm[idx] = T[st * 512 + sp * 256 + x * 64 + gp * 16 + z * 4 + g];
}

// Fixed-slot in-place contraction: state index = g*4096 + sum_j slot_j*4^j.
// Step (row,c) reads its up-bond x from slot c and writes its down-bond z
// back into slot c; the horizontal bond lives at slot 6 (the *4096 digit).
// Spectator digits never move -> thread-private read/write sets -> in-place
// update with ONE __syncthreads per step (36 total). State in LDS (64 KB),
// per-thread registers ~in[16][2]+acc -> spill-free at the 128-VGPR cap of
// __launch_bounds__(512,4): 2 blocks/CU (LDS-limited) x 8 waves = 50% occ.
// (R3/R6/R7 showed: occupancy is the binder, but the register-resident-state
// design couldn't be both spill-free and high-occupancy. This can.)
__global__ __launch_bounds__(512, 4)
void peps_amp_kernel(const int* __restrict__ X, const float* __restrict__ Tm,
                     float* __restrict__ out)
{
    __shared__ float W[16384];   // 65536 B exactly (4^7 fixed-slot state)

    const int b = blockIdx.x;
    const int t = threadIdx.x;
    const int* xrow = X + b * NSITE;

    // PHYS=2: pack the 36 spins into one scalar 64-bit mask (SGPR-resident
    // so the Tm addresses below are provably wave-uniform).
    unsigned long long sm = 0ull;
    const int4* xp = (const int4*)xrow;
    #pragma unroll
    for (int k = 0; k < 9; ++k) {
        int4 v = xp[k];
        sm |= ((unsigned long long)(v.x & 1)) << (4 * k + 0);
        sm |= ((unsigned long long)(v.y & 1)) << (4 * k + 1);
        sm |= ((unsigned long long)(v.z & 1)) << (4 * k + 2);
        sm |= ((unsigned long long)(v.w & 1)) << (4 * k + 3);
    }
    {
        unsigned lo = __builtin_amdgcn_readfirstlane((int)(sm & 0xffffffffull));
        unsigned hi = __builtin_amdgcn_readfirstlane((int)(sm >> 32));
        sm = ((unsigned long long)hi << 32) | lo;
    }

    if (t == 0) W[0] = 1.0f;     // seed; covered by the step-0 barrier

    const int u0 = 2 * t;        // this thread's two spectators: u0, u0+1
    int step = 0;
    for (int row = 0; row < NROW; ++row) {
        const int xs = (row == 0) ? 1 : 4;          // up-bond size
        const int zs = (row == NROW - 1) ? 1 : 4;   // down-bond size
        for (int c = 0; c < NCOL; ++c, ++step) {
            const int gin  = (c == 0) ? 1 : 4;
            const int gout = (c == NCOL - 1) ? 1 : 4;
            const int lowb  = (zs == 4) ? 2 * c : 0;       // live low slots
            const int highb = (xs == 4) ? 2 * (5 - c) : 0; // live high slots
            const int scount = 1 << (lowb + highb);        // spectator count
            const int spin = (int)((sm >> step) & 1ull);
            const float* Ms = Tm + (size_t)(step * 2 + spin) * 256; // uniform
            const int p4c = 1 << (2 * c);                  // 4^c
            const int lowmask = (1 << lowb) - 1;
            // spectator u -> address contribution (gap at slot c)
            const int mr0 = ((u0 >> lowb) << (2 * c + 2)) | (u0 & lowmask);
            const int mr1 = (((u0 + 1) >> lowb) << (2 * c + 2)) | ((u0 + 1) & lowmask);
            const bool act0 = (u0 < scount);
            const bool act1 = (u0 + 1 < scount);

            __syncthreads();     // the ONLY barrier per step

            if (act0) {
                // ---- read phase (thread-private addresses) ----
                float in[16][2];
                if (c == 0) {
                    // mr = 4u: x occupies the low digit -> b128 per (g, u)
                    #pragma unroll
                    for (int g = 0; g < 4; ++g) if (g < gin) {
                        float4 r0 = *(const float4*)&W[g * 4096 + 4 * u0];
                        in[g*4+0][0]=r0.x; in[g*4+1][0]=r0.y;
                        in[g*4+2][0]=r0.z; in[g*4+3][0]=r0.w;
                        if (act1) {
                            float4 r1 = *(const float4*)&W[g * 4096 + 4 * u0 + 4];
                            in[g*4+0][1]=r1.x; in[g*4+1][1]=r1.y;
                            in[g*4+2][1]=r1.z; in[g*4+3][1]=r1.w;
                        } else {
                            in[g*4+0][1]=0.f; in[g*4+1][1]=0.f;
                            in[g*4+2][1]=0.f; in[g*4+3][1]=0.f;
                        }
                    }
                } else if (zs == 4) {
                    // consecutive spectators adjacent -> b64 per (g,x)
                    #pragma unroll
                    for (int g = 0; g < 4; ++g) if (g < gin) {
                        #pragma unroll
                        for (int x = 0; x < 4; ++x) if (x < xs) {
                            float2 r = *(const float2*)&W[g * 4096 + x * p4c + mr0];
                            in[g*4+x][0] = r.x; in[g*4+x][1] = r.y;
                        }
                    }
                } else {
                    // row 5, c>=1: spectators far apart -> scalar reads (few
                    // active threads: scount <= 256)
                    #pragma unroll
                    for (int g = 0; g < 4; ++g) if (g < gin) {
                        #pragma unroll
                        for (int x = 0; x < 4; ++x) if (x < xs) {
                            in[g*4+x][0] = W[g * 4096 + x * p4c + mr0];
                            in[g*4+x][1] = act1 ? W[g * 4096 + x * p4c + mr1] : 0.f;
                        }
                    }
                }

                // ---- compute + write (in-place; same spectators) ----
                #pragma unroll
                for (int gp = 0; gp < 4; ++gp) if (gp < gout) {
                    float a[4][2];
                    #pragma unroll
                    for (int z = 0; z < 4; ++z) if (z < zs) {
                        float s0 = 0.f, s1 = 0.f;
                        #pragma unroll
                        for (int g = 0; g < 4; ++g) if (g < gin) {
                            const float4 mq =
                                *(const float4*)&Ms[(gp * 4 + z) * 16 + g * 4];
                            s0 += mq.x * in[g*4+0][0]; s1 += mq.x * in[g*4+0][1];
                            if (xs == 4) {
                                s0 += mq.y * in[g*4+1][0]; s1 += mq.y * in[g*4+1][1];
                                s0 += mq.z * in[g*4+2][0]; s1 += mq.z * in[g*4+2][1];
                                s0 += mq.w * in[g*4+3][0]; s1 += mq.w * in[g*4+3][1];
                            }
                        }
                        a[z][0] = s0; a[z][1] = s1;
                        if (c != 0 && zs == 4) {
                            // b64 write covers u0,u0+1 (act1==act0 here)
                            *(float2*)&W[gp * 4096 + z * p4c + mr0] =
                                make_float2(s0, s1);
                        } else if (zs == 1) {
                            W[gp * 4096 + mr0] = s0;
                            if (act1) W[gp * 4096 + mr1] = s1;
                        }
                    }
                    if (c == 0 && zs == 4) {
                        *(float4*)&W[gp * 4096 + 4 * u0] =
                            make_float4(a[0][0], a[1][0], a[2][0], a[3][0]);
                        if (act1)
                            *(float4*)&W[gp * 4096 + 4 * u0 + 4] =
                                make_float4(a[0][1], a[1][1], a[2][1], a[3][1]);
                    }
                }
            }
        }
    }
    __syncthreads();
    // after (5,5): only g'=0, z=0, u=0 live -> the amplitude sits at W[0]
    if (t == 0) out[b] = W[0];
}

extern "C" void kernel_launch(void* const* d_in, const int* in_sizes, int n_in,
                              void* d_out, int out_size, void* d_ws, size_t ws_size,
                              hipStream_t stream) {
    const int*   X  = (const int*)d_in[0];     // x: [1024, 36] int32
    const float* Tg = (const float*)d_in[1];   // T: [6,6,2,4,4,4,4] fp32
    float* out = (float*)d_out;                // reference output: float32
    float* Tm  = (float*)d_ws;                 // 73,728 B scratch
    (void)in_sizes; (void)n_in; (void)ws_size; (void)out_size;
    peps_reorder_kernel<<<dim3(72), dim3(256), 0, stream>>>(Tg, Tm);
    peps_amp_kernel<<<dim3(BATCH), dim3(512), 0, stream>>>(X, Tm, out);
}